// Round 11
// baseline (50.699 us; speedup 1.0000x reference)
//
#include <hip/hip_runtime.h>

#define NB 10   // labels 1..10
#define BATCH 8
#define EPSF 1e-6f

constexpr int THREADS          = 256;
constexpr int VEC_PER_BATCH    = (128 * 128 * 128) / 4;  // 524,288 float4 per batch
constexpr int BLOCKS_PER_BATCH = 96;
constexpr int GRID             = BLOCKS_PER_BATCH * BATCH; // 768 = 3 blocks/CU (LDS fits 3)
constexpr int WAVES_PER_BATCH  = BLOCKS_PER_BATCH * 4;     // 384
constexpr int ST_PER_BATCH     = VEC_PER_BATCH / 64;       // 8192 stage-triples per batch
constexpr int STQ              = ST_PER_BATCH / WAVES_PER_BATCH;      // 21
constexpr int STR              = ST_PER_BATCH - STQ * WAVES_PER_BATCH; // 128 waves get +1

// ws layout (transposed for coalesced finisher):
//   float rows 0..29: ws[idx*GRID + block]  (idx = which*10+lab; which 0:I 1:X 2:T)
//   uint  row  30:    presence mask per block
// every slot written unconditionally every call -> no zeroing needed.

// async global->LDS DMA, 16B/lane: dest = wave-uniform base + lane*16 (linear),
// source = per-lane address. No VGPR destinations -> no spill fight.
__device__ __forceinline__ void dma16(const void* g, void* l) {
    __builtin_amdgcn_global_load_lds(
        (const __attribute__((address_space(1))) void*)g,
        (__attribute__((address_space(3))) void*)l, 16, 0, 0);
}

__global__ __launch_bounds__(THREADS)
void dice_partial(const float* __restrict__ x,
                  const float* __restrict__ t,
                  const int*   __restrict__ s,
                  float* __restrict__ ws)
{
    // per-wave private 4-deep ring buffers: no __syncthreads in main loop
    __shared__ float4 lx[4][4][64];   // [wave][buf][lane]
    __shared__ float4 lt[4][4][64];
    __shared__ int4   lsb[4][4][64];

    const int tid  = threadIdx.x;
    const int wave = tid >> 6, lane = tid & 63;
    const int batch = blockIdx.x / BLOCKS_PER_BATCH;
    const int sub   = blockIdx.x % BLOCKS_PER_BATCH;
    const int wb    = sub * 4 + wave;                 // wave id within batch, 0..383
    const int NSTG  = STQ + (wb < STR ? 1 : 0);       // 21 or 22 stages for this wave
    const long long start = (long long)batch * VEC_PER_BATCH
                          + ((long long)wb * STQ + (wb < STR ? wb : STR)) * 64 + lane;

    const float4* gx = (const float4*)x + start;
    const float4* gt = (const float4*)t + start;
    const int4*   gs = (const int4*)s  + start;

    float aI[NB], aX[NB], aT[NB];
#pragma unroll
    for (int k = 0; k < NB; ++k) { aI[k] = 0.f; aX[k] = 0.f; aT[k] = 0.f; }
    unsigned bits = 0;   // bit v set <=> label value v seen

#define DO_ELEM(xe, te, se)                                     \
    do {                                                        \
        const float _x = (xe), _t = (te);                       \
        const int   _s = (se);                                  \
        const float _p = _x * _t;                               \
        bits |= (1u << _s);                                     \
        _Pragma("unroll")                                       \
        for (int k = 0; k < NB; ++k) {                          \
            const float m = (_s == k + 1) ? 1.0f : 0.0f;        \
            aI[k] = fmaf(m, _p, aI[k]);                         \
            aX[k] = fmaf(m, _x, aX[k]);                         \
            aT[k] = fmaf(m, _t, aT[k]);                         \
        }                                                       \
    } while (0)

    // prologue: DMA stages 0..2 (9 outstanding vmcnt events); NSTG >= 21 always
#pragma unroll
    for (int i = 0; i < 3; ++i) {
        dma16(gx + i * 64, &lx[wave][i][0]);
        dma16(gt + i * 64, &lt[wave][i][0]);
        dma16(gs + i * 64, &lsb[wave][i][0]);
    }
    const float4* px = gx + 3 * 64;   // prefetch pointers
    const float4* pt = gt + 3 * 64;
    const int4*   ps = gs + 3 * 64;

#pragma unroll 1
    for (int i = 0; i < NSTG; ++i) {
        // counted wait: stage i retired; up to 2 younger stages (6 DMAs) in flight
        if (i < NSTG - 2)       asm volatile("s_waitcnt vmcnt(6)" ::: "memory");
        else if (i == NSTG - 2) asm volatile("s_waitcnt vmcnt(3)" ::: "memory");
        else                    asm volatile("s_waitcnt vmcnt(0)" ::: "memory");
        __builtin_amdgcn_sched_barrier(0);

        if (i + 3 < NSTG) {     // issue stage i+3 into the freed buffer
            const int nb = (i + 3) & 3;
            dma16(px, &lx[wave][nb][0]);
            dma16(pt, &lt[wave][nb][0]);
            dma16(ps, &lsb[wave][nb][0]);
            px += 64; pt += 64; ps += 64;
        }

        const int b = i & 3;    // consume stage i (3x ds_read_b128)
        const float4 xv = lx[wave][b][lane];
        const float4 tv = lt[wave][b][lane];
        const int4   sv = lsb[wave][b][lane];
        DO_ELEM(xv.x, tv.x, sv.x);
        DO_ELEM(xv.y, tv.y, sv.y);
        DO_ELEM(xv.z, tv.z, sv.z);
        DO_ELEM(xv.w, tv.w, sv.w);
    }
#undef DO_ELEM

    // wave-64 butterfly (once per block)
#pragma unroll
    for (int k = 0; k < NB; ++k) {
#pragma unroll
        for (int off = 32; off > 0; off >>= 1) {
            aI[k] += __shfl_xor(aI[k], off);
            aX[k] += __shfl_xor(aX[k], off);
            aT[k] += __shfl_xor(aT[k], off);
        }
    }
#pragma unroll
    for (int off = 32; off > 0; off >>= 1)
        bits |= (unsigned)__shfl_xor((int)bits, off);

    // cross-wave combine in LDS, then transposed plain stores
    __shared__ float    wsum[4][32];
    __shared__ unsigned wbm[4];
    if (lane < NB) {
        wsum[wave][lane]          = aI[lane];
        wsum[wave][NB + lane]     = aX[lane];
        wsum[wave][2 * NB + lane] = aT[lane];
    }
    if (lane == 0) wbm[wave] = bits;
    __syncthreads();

    if (tid < 3 * NB) {   // row idx = tid, column = blockIdx.x
        const float v = wsum[0][tid] + wsum[1][tid] + wsum[2][tid] + wsum[3][tid];
        ws[tid * GRID + blockIdx.x] = v;
    }
    if (tid == 0)
        ((unsigned*)ws)[3 * NB * GRID + blockIdx.x] = wbm[0] | wbm[1] | wbm[2] | wbm[3];
}

__global__ void dice_final(const float* __restrict__ ws, float* __restrict__ out)
{
    const int tid = threadIdx.x;
    __shared__ float    sums[BATCH * 3 * NB];   // [batch*30 + idx]
    __shared__ unsigned um[THREADS];

    // phase 1: 240 combos; 16 groups of 16 lanes, 15 combos each.
    // combo c: batch=c/30, idx=c%30 -> 96 contiguous floats at ws[idx*GRID+batch*96]
    const int grp = tid >> 4, l16 = tid & 15;
#pragma unroll
    for (int j = 0; j < 15; ++j) {
        const int c = grp + 16 * j;             // 0..239
        const int batch = c / (3 * NB);
        const int idx   = c % (3 * NB);
        const int base  = idx * GRID + batch * BLOCKS_PER_BATCH;
        float v = 0.0f;
#pragma unroll
        for (int q = 0; q < BLOCKS_PER_BATCH / 16; ++q)   // 6 coalesced 64B bursts
            v += ws[base + q * 16 + l16];
        v += __shfl_xor(v, 8);
        v += __shfl_xor(v, 4);
        v += __shfl_xor(v, 2);
        v += __shfl_xor(v, 1);
        if (l16 == 0) sums[c] = v;
    }

    // phase 2: OR all 768 presence masks
    const unsigned* mrow = (const unsigned*)ws + 3 * NB * GRID;
    um[tid] = mrow[tid] | mrow[tid + 256] | mrow[tid + 512];
    __syncthreads();
    for (int st = THREADS / 2; st > 0; st >>= 1) {
        if (tid < st) um[tid] |= um[tid + st];
        __syncthreads();
    }
    const unsigned mask = um[0];   // bit v = label value v present (v=1..10)

    // phase 3: dice per label, reduce over labels (first wave only)
    if (tid < 64) {
        float lpb = 0.0f, pres = 0.0f;
        if (tid < NB) {
            float sum_loss = 0.0f, valid = 0.0f;
            for (int b = 0; b < BATCH; ++b) {
                const float I = sums[b * 3 * NB + tid];
                const float X = sums[b * 3 * NB + NB + tid];
                const float T = sums[b * 3 * NB + 2 * NB + tid];
                const float denom = X + T + 2.0f * EPSF;
                float bl = 1.0f - 2.0f * I / denom;
                if (T == 0.0f) bl = 0.0f; else valid += 1.0f;
                sum_loss += bl;
            }
            lpb  = sum_loss / fmaxf(valid, 1.0f);
            pres = ((mask >> (tid + 1)) & 1u) ? 1.0f : 0.0f;
        }
        float num = pres;
        float ls  = (pres > 0.0f) ? lpb : 0.0f;
#pragma unroll
        for (int off = 32; off > 0; off >>= 1) {
            num += __shfl_down(num, off);
            ls  += __shfl_down(ls,  off);
        }
        if (tid == 0) {
            out[0] = ls / num;
            out[1] = 0.0f;
        }
    }
}

extern "C" void kernel_launch(void* const* d_in, const int* in_sizes, int n_in,
                              void* d_out, int out_size, void* d_ws, size_t ws_size,
                              hipStream_t stream)
{
    const float* x = (const float*)d_in[0];
    const float* t = (const float*)d_in[1];
    const int*   s = (const int*)d_in[2];
    float* out = (float*)d_out;
    float* ws  = (float*)d_ws;

    dice_partial<<<GRID, THREADS, 0, stream>>>(x, t, s, ws);
    dice_final<<<1, THREADS, 0, stream>>>(ws, out);
}